// Round 5
// baseline (145.708 us; speedup 1.0000x reference)
//
#include <hip/hip_runtime.h>
#include <math.h>

// LowRankChristoffel: out = clip((((v@U)^2) @ W^T) * (1+sigmoid(x@Vw^T)), +-5)
// B=4, S=4096, D=2048, R=16, fp32.
//
// R5: R4 fixed spills (WRITE 635->132 MB) but occupancy capped at 39.5% by the
// 137 KiB LDS (1 block/CU). Fix: transpose U into d_ws with a tiny prologue
// kernel; main kernel reads U^T *from global* (coalesced, L2-resident 128 KiB
// per XCD) instead of LDS. LDS drops to 2.2 KiB, ROWS 64->32, grid 512 ->
// 2 blocks/CU (requires the proven-64-VGPR RB=2 body -> no waves_per_eu pin).

constexpr int D_DIM   = 2048;
constexpr int R_DIM   = 16;
constexpr int ROWS    = 32;       // rows per block
constexpr int THREADS = 1024;     // 16 waves
constexpr int WAVES   = THREADS / 64;
constexpr int RB      = 2;        // rows per wave (one batch)

typedef float f32x2 __attribute__((ext_vector_type(2)));

__device__ __forceinline__ float clamp5(float v) {
    return fminf(fmaxf(v, -5.0f), 5.0f);
}
__device__ __forceinline__ float dot4(float4 a, float4 b) {
    return a.x * b.x + a.y * b.y + a.z * b.z + a.w * b.w;
}

// ---- prologue: U [2048][16] -> Ut [16][2048] (runs every call; ~3 us) ----
extern "C" __global__ void transpose_u(const float* __restrict__ U,
                                       float* __restrict__ Ut) {
    const int o = blockIdx.x * blockDim.x + threadIdx.x;   // output-linear
    if (o < R_DIM * D_DIM) {
        const int r = o >> 11;          // / 2048
        const int d = o & (D_DIM - 1);  // % 2048
        Ut[o] = U[(d << 4) + r];        // coalesced writes, L2-resident reads
    }
}

extern "C" __global__ void __launch_bounds__(THREADS)
lrc_kernel(const float* __restrict__ v, const float* __restrict__ x,
           const float* __restrict__ Ut, const float* __restrict__ W,
           const float* __restrict__ Vw, float* __restrict__ out, int nrows)
{
    __shared__ float sq_lds[ROWS * R_DIM];   // [32][16]
    __shared__ float fac_lds[ROWS];

    const int tid  = threadIdx.x;
    const int lane = tid & 63;
    const int wave = tid >> 6;          // 0..15
    const int row0 = blockIdx.x * ROWS;

    // ---- phase 1: each wave computes proj^2 + modulation for RB=2 rows ----
    {
        const int rl0 = wave * RB;
        const float* vb = v + (size_t)(row0 + rl0) * D_DIM;
        const float* xb = x + (size_t)(row0 + rl0) * D_DIM;

        float pp[RB][R_DIM];
        float xv[RB];
        #pragma unroll
        for (int k = 0; k < RB; ++k) {
            xv[k] = 0.0f;
            #pragma unroll
            for (int r = 0; r < R_DIM; ++r) pp[k][r] = 0.0f;
        }

        for (int i = 0; i < D_DIM / 256; ++i) {    // 8 iters, 256 floats/wave/iter
            const int d0 = i * 256 + lane * 4;
            float4 v4[RB], x4[RB];
            #pragma unroll
            for (int k = 0; k < RB; ++k) {
                v4[k] = *reinterpret_cast<const float4*>(vb + (size_t)k * D_DIM + d0);
                x4[k] = *reinterpret_cast<const float4*>(xb + (size_t)k * D_DIM + d0);
            }
            const float4 vw4 = *reinterpret_cast<const float4*>(Vw + d0);  // L2 broadcast
            #pragma unroll
            for (int k = 0; k < RB; ++k) xv[k] += dot4(x4[k], vw4);
            #pragma unroll
            for (int r = 0; r < R_DIM; ++r) {
                const float4 u4 =
                    *reinterpret_cast<const float4*>(Ut + r * D_DIM + d0);  // L2-hit, coalesced
                #pragma unroll
                for (int k = 0; k < RB; ++k) pp[k][r] += dot4(v4[k], u4);
            }
        }

        // butterfly reduce across the 64-lane wave
        #pragma unroll
        for (int s = 32; s >= 1; s >>= 1) {
            #pragma unroll
            for (int k = 0; k < RB; ++k) {
                xv[k] += __shfl_xor(xv[k], s, 64);
                #pragma unroll
                for (int r = 0; r < R_DIM; ++r) pp[k][r] += __shfl_xor(pp[k][r], s, 64);
            }
        }
        if (lane == 0) {
            #pragma unroll
            for (int k = 0; k < RB; ++k) {
                const int rl = rl0 + k;
                if (row0 + rl < nrows) {
                    #pragma unroll
                    for (int r = 0; r < R_DIM; ++r)
                        sq_lds[rl * R_DIM + r] = pp[k][r] * pp[k][r];
                    fac_lds[rl] = 1.0f + 1.0f / (1.0f + __expf(-xv[k]));
                }
            }
        }
    }
    __syncthreads();

    // ---- phase 2: thread owns d = 2*tid, 2*tid+1; W in registers ----
    {
        const int dd = tid * 2;
        float w0[R_DIM], w1[R_DIM];
        const float4* p0 = reinterpret_cast<const float4*>(W + (size_t)dd * R_DIM);
        const float4* p1 = reinterpret_cast<const float4*>(W + (size_t)(dd + 1) * R_DIM);
        #pragma unroll
        for (int c = 0; c < 4; ++c) {
            *reinterpret_cast<float4*>(&w0[c * 4]) = p0[c];
            *reinterpret_cast<float4*>(&w1[c * 4]) = p1[c];
        }

        for (int rl = 0; rl < ROWS; ++rl) {
            if (row0 + rl >= nrows) break;
            float sqv[R_DIM];
            #pragma unroll
            for (int c = 0; c < 4; ++c)
                *reinterpret_cast<float4*>(&sqv[c * 4]) =
                    *reinterpret_cast<const float4*>(sq_lds + rl * R_DIM + c * 4);
            const float fac = fac_lds[rl];
            float o0 = 0.0f, o1 = 0.0f;
            #pragma unroll
            for (int r = 0; r < R_DIM; ++r) {
                o0 += sqv[r] * w0[r];
                o1 += sqv[r] * w1[r];
            }
            f32x2 o;
            o.x = clamp5(o0 * fac);
            o.y = clamp5(o1 * fac);
            __builtin_nontemporal_store(o,
                reinterpret_cast<f32x2*>(out + (size_t)(row0 + rl) * D_DIM + dd));
        }
    }
}

extern "C" void kernel_launch(void* const* d_in, const int* in_sizes, int n_in,
                              void* d_out, int out_size, void* d_ws, size_t ws_size,
                              hipStream_t stream) {
    const float* v  = (const float*)d_in[0];
    const float* x  = (const float*)d_in[1];
    const float* U  = (const float*)d_in[2];
    const float* W  = (const float*)d_in[3];
    const float* Vw = (const float*)d_in[4];
    float* out = (float*)d_out;
    float* Ut  = (float*)d_ws;                    // 128 KiB scratch

    const int nrows = in_sizes[0] / D_DIM;        // B*S = 16384
    const int grid  = (nrows + ROWS - 1) / ROWS;  // 512

    transpose_u<<<(R_DIM * D_DIM + 255) / 256, 256, 0, stream>>>(U, Ut);
    lrc_kernel<<<grid, THREADS, 0, stream>>>(v, x, Ut, W, Vw, out, nrows);
}